// Round 3
// baseline (647.147 us; speedup 1.0000x reference)
//
#include <hip/hip_runtime.h>

#define BATCH 32
#define TIME  512
#define INF   512
#define HIDF  1024

// ---------------------------------------------------------------------------
// Phase 1: hidden[bt][h] = (sum_i x[bt,i]*W[h,i]) + bias[h], emulating the
// canonical XLA GEMM order: per output element a SINGLE fp32 accumulator,
// FUSED fma, k walked ASCENDING 0..511, then ONE fp32 rounding for +bias.
// (Covers both Eigen gebp on XLA:CPU and Tensile/hipblaslt fp32 on XLA:GPU.)
// Thread = 1 h x 8 bt-rows -> 8 independent FMA chains for ILP.
// ---------------------------------------------------------------------------
__global__ __launch_bounds__(256, 3)
void snn_gemm_seqfma(const float* __restrict__ x, const float* __restrict__ W,
                     const float* __restrict__ bias, float* __restrict__ hidden) {
    const int lane = threadIdx.x & 63;
    const int wv   = __builtin_amdgcn_readfirstlane((int)(threadIdx.x >> 6)); // wave 0..3
    const int h    = blockIdx.x * 64 + lane;
    const int bt0  = blockIdx.y * 32 + wv * 8;     // this wave's 8 bt rows

    float acc[8];
    #pragma unroll
    for (int t = 0; t < 8; ++t) acc[t] = 0.0f;

    const float* Wrow = W + (size_t)h * INF;

    for (int chunk = 0; chunk < 8; ++chunk) {      // 64 k per chunk
        float w[64];
        const float4* wp = (const float4*)(Wrow + chunk * 64);
        #pragma unroll
        for (int q = 0; q < 16; ++q) {
            float4 v = wp[q];
            w[4*q+0] = v.x; w[4*q+1] = v.y; w[4*q+2] = v.z; w[4*q+3] = v.w;
        }
        #pragma unroll
        for (int t = 0; t < 8; ++t) {
            // wave-uniform address -> scalar loads
            const float4* xp = (const float4*)(x + (size_t)(bt0 + t) * INF + chunk * 64);
            #pragma unroll
            for (int q = 0; q < 16; ++q) {
                float4 xv = xp[q];
                // strictly ascending k, fused fma, single accumulator
                acc[t] = __fmaf_rn(xv.x, w[4*q+0], acc[t]);
                acc[t] = __fmaf_rn(xv.y, w[4*q+1], acc[t]);
                acc[t] = __fmaf_rn(xv.z, w[4*q+2], acc[t]);
                acc[t] = __fmaf_rn(xv.w, w[4*q+3], acc[t]);
            }
        }
    }

    const float bv = bias[h];
    #pragma unroll
    for (int t = 0; t < 8; ++t) {
        float hv = __fadd_rn(acc[t], bv);           // one rounding for bias
        hidden[(size_t)(bt0 + t) * HIDF + h] = hv;  // coalesced over h
    }
}

// ---------------------------------------------------------------------------
// Phase 2: in-place LIF scan over t per (b,h) column, fp32:
//   mem = fl32(0.5*mem + h_t)  (0.5*mem exact, so fused/unfused identical);
//   spk = mem > 1.0f; hard reset.
// ---------------------------------------------------------------------------
__global__ __launch_bounds__(256)
void snn_scan_np(float* __restrict__ io) {
    const int n = blockIdx.x * 256 + threadIdx.x;   // 0..32767
    const int b = n >> 10;
    const int h = n & 1023;
    float* p = io + (size_t)b * TIME * HIDF + h;

    float mem = 0.0f;
    for (int tb = 0; tb < TIME / 16; ++tb) {
        float hv[16];
        #pragma unroll
        for (int u = 0; u < 16; ++u) hv[u] = p[(size_t)(tb * 16 + u) * HIDF];
        float sp[16];
        #pragma unroll
        for (int u = 0; u < 16; ++u) {
            mem = __fadd_rn(__fmul_rn(0.5f, mem), hv[u]);
            bool s = mem > 1.0f;
            sp[u] = s ? 1.0f : 0.0f;
            if (s) mem = 0.0f;
        }
        #pragma unroll
        for (int u = 0; u < 16; ++u) p[(size_t)(tb * 16 + u) * HIDF] = sp[u];
    }
}

extern "C" void kernel_launch(void* const* d_in, const int* in_sizes, int n_in,
                              void* d_out, int out_size, void* d_ws, size_t ws_size,
                              hipStream_t stream) {
    const float* x    = (const float*)d_in[0];   // [32, 512, 512]
    const float* W    = (const float*)d_in[1];   // [1024, 512]
    const float* bias = (const float*)d_in[2];   // [1024]
    float* out = (float*)d_out;                  // [32, 512, 1024]

    dim3 g1(HIDF / 64, (BATCH * TIME) / 32);     // (16, 512)
    snn_gemm_seqfma<<<g1, 256, 0, stream>>>(x, W, bias, out);

    snn_scan_np<<<(BATCH * HIDF) / 256, 256, 0, stream>>>(out);
}